// Round 14
// baseline (125.418 us; speedup 1.0000x reference)
//
#include <hip/hip_runtime.h>
#include <hip/hip_bf16.h>
#include <stdint.h>

// Problem constants: N=4096, T=16, D=700 (pad 704), C=128, NC=20
// Output layout (f32): out0 [4096,20] | features [16,4096,128] | attended [16,4096,128]

typedef __attribute__((ext_vector_type(8))) _Float16 half8;  // f16x8 MFMA frag
typedef __attribute__((ext_vector_type(4))) float f32x4;
typedef unsigned long long u64;

#define MFMA16F(a, b, c) __builtin_amdgcn_mfma_f32_16x16x32_f16(a, b, c, 0, 0, 0)

__device__ inline void gload16(const void* g, void* l) {
  __builtin_amdgcn_global_load_lds(
      (const __attribute__((address_space(1))) uint32_t*)g,
      (__attribute__((address_space(3))) uint32_t*)l, 16, 0, 0);
}

__device__ inline u64 shfl64(u64 v, int src) {
  int lo = __shfl((int)(unsigned)(v & 0xffffffffu), src);
  int hi = __shfl((int)(unsigned)(v >> 32), src);
  return ((u64)(unsigned)hi << 32) | (unsigned)lo;
}

// ---------------------------------------------------------------------------
// f16 2-plane split with subnormal-avoiding scales:
//   a = h*2^-4 + l*2^-15 + ra,  |ra| <= 2^-24|a|   (RNE both planes)
// ---------------------------------------------------------------------------
__device__ inline void splitf16(float4 q0, float4 q1, half8& hh, half8& ll) {
  float f[8] = {q0.x, q0.y, q0.z, q0.w, q1.x, q1.y, q1.z, q1.w};
  _Float16 H[8], L[8];
#pragma unroll
  for (int j = 0; j < 8; ++j) {
    _Float16 h1 = (_Float16)(f[j] * 16.0f);          // RNE
    float r = fmaf((float)h1, -0.0625f, f[j]);       // exact residual
    L[j] = (_Float16)(r * 32768.0f);                 // 2^15, RNE
    H[j] = h1;
  }
  __builtin_memcpy(&hh, H, 16);
  __builtin_memcpy(&ll, L, 16);
}

// ---------------------------------------------------------------------------
// Prep: transpose WrT/W2T/WpT + split W_in into 2 f16 planes (k-pad 704)
//   b = p1*2^-8 + p2*2^-19 + rb, |rb| <= 2^-24|b|
// ---------------------------------------------------------------------------
__global__ void k_prep(const float* __restrict__ Wr, const float* __restrict__ W2,
                       const float* __restrict__ Wp, const float* __restrict__ Win,
                       float* __restrict__ WrT, float* __restrict__ W2T,
                       float* __restrict__ WpT, ushort* __restrict__ F2) {
  int idx = blockIdx.x * blockDim.x + threadIdx.x;
  if (idx < 3 * 16384) {
    int sel = idx >> 14;
    int r = idx & 16383;
    int j = r >> 7, c = r & 127;
    const float* src = (sel == 0) ? Wr : (sel == 1) ? W2 : Wp;
    float* dst = (sel == 0) ? WrT : (sel == 1) ? W2T : WpT;
    dst[r] = src[c * 128 + j];
  } else {
    int i2 = idx - 49152;
    if (i2 >= 128 * 704) return;
    int c = i2 / 704, d = i2 - c * 704;
    float w = (d < 700) ? Win[c * 700 + d] : 0.f;
    _Float16 b1 = (_Float16)(w * 256.0f);            // RNE, scale 2^8
    float r = fmaf((float)b1, -0.00390625f, w);      // exact residual
    _Float16 b2 = (_Float16)(r * 524288.0f);         // scale 2^19, RNE
    ushort u1, u2;
    __builtin_memcpy(&u1, &b1, 2);
    __builtin_memcpy(&u2, &b2, 2);
    F2[i2] = u1;
    F2[90112 + i2] = u2;
  }
}

// ---------------------------------------------------------------------------
// Fused GEMM + scan, 5 desynced blocks/CU. R10 K-loop EXACTLY (best known):
// tile 64x128, 256 threads, 4 waves, wave = 16 rows x 128 cols = ONE sample;
// A direct global->VGPR prefetched 1 kt ahead; B LDS dbuf 32KB via gload16;
// one __syncthreads per kt. LDS = 32768 exactly (XWs[64][128] XOR-swizzled
// overlays the dbuf); ALL scan scratch in registers via shfl -> 5 blocks/CU.
// ---------------------------------------------------------------------------
__global__ __launch_bounds__(256, 5) void k_gemm_scan(
    const float* __restrict__ x, const ushort* __restrict__ F2,
    const float* __restrict__ b_in, const float* __restrict__ b_rec,
    const float* __restrict__ WrT, const float* __restrict__ W2T,
    const float* __restrict__ b2, const float* __restrict__ WpT,
    const float* __restrict__ b_p, const float* __restrict__ W_out,
    const float* __restrict__ b_out, const float* __restrict__ k_t,
    const float* __restrict__ k_c, float* __restrict__ features,
    float* __restrict__ attended, float* __restrict__ out0) {
  __shared__ __align__(16) char lds[32768];  // B dbuf 2x16KB; then XWs[64][128]

  const int tid = threadIdx.x;
  const int w = tid >> 6;      // wave 0..3 = 16-row group = sample
  const int l = tid & 63;
  const int blk = blockIdx.x;
  const int lm = l & 15, kh = l >> 4;

  // --- A: direct per-lane loads; rows m = blk*64 + w*16 + lm contiguous in x.
  const float* xr = x + (size_t)(blk * 64 + w * 16 + lm) * 700;

  // --- B staging: 16 gload16/block-kt (2 planes x 8 col-groups), wave does 4.
  const ushort* bsrc[4];
  int bdst[4];
#pragma unroll
  for (int i = 0; i < 4; ++i) {
    int idx = w * 4 + i;
    int plane = idx >> 3, cg = idx & 7;
    int col = cg * 16 + (l >> 2);
    bsrc[i] = F2 + plane * 90112 + col * 704 + (((l & 3) ^ ((l >> 3) & 3)) * 8);
    bdst[i] = plane * 8192 + cg * 1024;
  }
  const int bkey = (lm >> 1) & 3;
  const int brd = lm * 64 + ((kh ^ bkey) * 16);

  f32x4 acc_h[8], acc_m[8];
#pragma unroll
  for (int j = 0; j < 8; ++j) {
    acc_h[j] = (f32x4){0.f, 0.f, 0.f, 0.f};
    acc_m[j] = (f32x4){0.f, 0.f, 0.f, 0.f};
  }

  auto STAGE = [&](int buf, int kt) {  // 4 gload_lds per wave
    const int k0 = kt * 32;
#pragma unroll
    for (int i = 0; i < 4; ++i)
      gload16(bsrc[i] + k0, lds + buf * 16384 + bdst[i]);
  };
  auto LOADA = [&](int kt, float4& q0, float4& q1) {
    const int k0 = kt * 32 + kh * 8;
    q0 = *(const float4*)(xr + k0);
    if (kt == 21 && kh == 3)
      q1 = make_float4(0.f, 0.f, 0.f, 0.f);  // k 700..703: B-pad is zero
    else
      q1 = *(const float4*)(xr + k0 + 4);
  };

  STAGE(0, 0);
  float4 qa, qb;
  LOADA(0, qa, qb);
  __syncthreads();
  int buf = 0;
  for (int kt = 0; kt < 22; ++kt) {
    float4 na = {}, nb = {};
    if (kt < 21) {
      STAGE(buf ^ 1, kt + 1);
      LOADA(kt + 1, na, nb);
    }
    half8 a1, a2;
    splitf16(qa, qb, a1, a2);
    const char* bb0 = lds + buf * 16384 + brd;
#pragma unroll
    for (int nf = 0; nf < 8; ++nf) {
      const char* bb = bb0 + nf * 1024;
      half8 b1 = *(const half8*)(bb);
      half8 b2f = *(const half8*)(bb + 8192);
      acc_h[nf] = MFMA16F(a1, b1, acc_h[nf]);
      acc_m[nf] = MFMA16F(a1, b2f, acc_m[nf]);
      acc_m[nf] = MFMA16F(a2, b1, acc_m[nf]);
    }
    __syncthreads();   // buf consumed by all waves; next-kt loads drained
    qa = na; qb = nb;
    buf ^= 1;
  }

  // --- Epilogue (wave-local): acc -> XWs[64][128] with XOR swizzle
  // colx = col ^ (((row>>2)&3)<<3); for rows kh*4+r the key is kh<<3.
  float* XWs = (float*)lds;
#pragma unroll
  for (int nf = 0; nf < 8; ++nf) {
    const int col = nf * 16 + lm;
    const float bias = b_in[col] + b_rec[col];
    const int colx = col ^ (kh << 3);
    const int rowb = w * 16 + kh * 4;
#pragma unroll
    for (int r = 0; r < 4; ++r)
      XWs[(rowb + r) * 128 + colx] =
          acc_h[nf][r] * 0.000244140625f +
          acc_m[nf][r] * 1.1920928955078125e-7f + bias;
  }
  // No barrier: wave w reads only its own rows w*16.. (wave-ordered LDS).

  // ========== wave-per-sample scan: ALL scratch in registers (shfl) ========
  const int n_glob = blk * 4 + w;

  const float b2a = b2[l], b2b = b2[l + 64];
  float v1a = 0.f, v1b = 0.f, v2a = 0.f, v2b = 0.f, fsa = 0.f, fsb = 0.f;
  u64 pm0 = 0ull, pm1 = 0ull;            // layer-1 spike masks (regs)
  u64 fm0 = 0ull, fm1 = 0ull;            // feature-mask slot (lane t holds t)
  float pcv = 0.f;                       // popcount slot (lane t holds t)

  for (int t = 0; t < 16; ++t) {
    const float* xrow = XWs + (w * 16 + t) * 128;
    const int key = ((t >> 2) & 3) << 3;
    float ia = xrow[l ^ key];
    float ib = xrow[(l + 64) ^ key];
    u64 q0 = pm0, q1 = pm1;
    while (q0) { int j = __builtin_ctzll(q0); q0 &= q0 - 1;
      ia += WrT[j * 128 + l]; ib += WrT[j * 128 + l + 64]; }
    while (q1) { int j = __builtin_ctzll(q1); q1 &= q1 - 1;
      ia += WrT[(64 + j) * 128 + l]; ib += WrT[(64 + j) * 128 + l + 64]; }
    v1a = v1a + (ia - v1a) * 0.5f;       // decay_input=True, TAU=2
    bool sa = (v1a - 1.0f) >= 0.f; v1a = sa ? 0.f : v1a;
    v1b = v1b + (ib - v1b) * 0.5f;
    bool sb = (v1b - 1.0f) >= 0.f; v1b = sb ? 0.f : v1b;
    pm0 = __ballot((int)sa);
    pm1 = __ballot((int)sb);
    float xa = b2a, xb = b2b;
    u64 r0 = pm0, r1 = pm1;
    while (r0) { int j = __builtin_ctzll(r0); r0 &= r0 - 1;
      xa += W2T[j * 128 + l]; xb += W2T[j * 128 + l + 64]; }
    while (r1) { int j = __builtin_ctzll(r1); r1 &= r1 - 1;
      xa += W2T[(64 + j) * 128 + l]; xb += W2T[(64 + j) * 128 + l + 64]; }
    v2a = v2a + (xa - v2a) * 0.5f;
    bool fa = (v2a - 1.0f) >= 0.f; v2a = fa ? 0.f : v2a;
    v2b = v2b + (xb - v2b) * 0.5f;
    bool fb = (v2b - 1.0f) >= 0.f; v2b = fb ? 0.f : v2b;
    float ffa = fa ? 1.f : 0.f, ffb = fb ? 1.f : 0.f;
    features[(size_t)((t << 12) | n_glob) * 128 + l] = ffa;
    features[(size_t)((t << 12) | n_glob) * 128 + l + 64] = ffb;
    fsa += ffa; fsb += ffb;
    u64 f0 = __ballot((int)fa), f1 = __ballot((int)fb);
    if (l == t) {   // lane t keeps timestep t's masks + popcount
      fm0 = f0; fm1 = f1;
      pcv = (float)(__popcll(f0) + __popcll(f1));
    }
  }

  // mean0 per channel (regs): msa = ch l, msb = ch l+64
  const float msa = fsa * (1.f / 16.f);
  const float msb = fsb * (1.f / 16.f);

  // t_att (computed on all lanes; only lanes 0..15 meaningful)
  float tav = 0.f;
  {
    float acc = 0.f;
#pragma unroll
    for (int j = 0; j < 3; ++j) {
      int tt = l - 1 + j;
      float pv = __shfl(pcv, (tt & 63));
      if (tt >= 0 && tt < 16) {
        float m = pv * (1.f / 128.f);
        acc += k_t[j] * m;
      }
    }
    tav = 1.f / (1.f + expf(-acc));
  }
  // c_att for both channels (neighbors via shfl; OOB = 0)
  float caa, cab;
  {
    float lft = __shfl(msa, (l == 0) ? 0 : (l - 1));
    float nm1 = (l == 0) ? 0.f : lft;
    float rgt = (l == 63) ? __shfl(msb, 0) : __shfl(msa, (l + 1) & 63);
    caa = 1.f / (1.f + expf(-(k_c[0] * nm1 + k_c[1] * msa + k_c[2] * rgt)));
    float lftb = (l == 0) ? __shfl(msa, 63) : __shfl(msb, (l - 1) & 63);
    float rgtb_raw = __shfl(msb, (l + 1) & 63);
    float rgtb = (l == 63) ? 0.f : rgtb_raw;
    cab = 1.f / (1.f + expf(-(k_c[0] * lftb + k_c[1] * msb + k_c[2] * rgtb)));
  }

  // ---- phase 2: attended + LIF layer3 + spike-count (wave-local) ----
  const float bpa = b_p[l], bpb = b_p[l + 64];
  float v3a = 0.f, v3b = 0.f, ssa = 0.f, ssb = 0.f;
  for (int t = 0; t < 16; ++t) {
    u64 m0 = shfl64(fm0, t), m1 = shfl64(fm1, t);
    float tat = __shfl(tav, t);
    bool ba = (m0 >> l) & 1, bb = (m1 >> l) & 1;
    attended[(size_t)((t << 12) | n_glob) * 128 + l] = ba ? tat * caa : 0.f;
    attended[(size_t)((t << 12) | n_glob) * 128 + l + 64] = bb ? tat * cab : 0.f;
    float ha = bpa, hb = bpb;
    u64 q0 = m0, q1 = m1;
    while (q0) { int j = __builtin_ctzll(q0); q0 &= q0 - 1;   // j wave-uniform
      float w_ = tat * __shfl(caa, j);
      ha += w_ * WpT[j * 128 + l]; hb += w_ * WpT[j * 128 + l + 64]; }
    while (q1) { int j = __builtin_ctzll(q1); q1 &= q1 - 1;
      float w_ = tat * __shfl(cab, j);
      ha += w_ * WpT[(64 + j) * 128 + l]; hb += w_ * WpT[(64 + j) * 128 + l + 64]; }
    v3a = v3a + (ha - v3a) * 0.5f;
    bool sa = (v3a - 1.0f) >= 0.f; v3a = sa ? 0.f : v3a;
    ssa += sa ? 1.f : 0.f;
    v3b = v3b + (hb - v3b) * 0.5f;
    bool sb = (v3b - 1.0f) >= 0.f; v3b = sb ? 0.f : v3b;
    ssb += sb ? 1.f : 0.f;
  }
  const float gsa = ssa * (1.f / 16.f);
  const float gsb = ssb * (1.f / 16.f);

  // Final 20-class projection: g[j] via shfl (uniform j), lanes <20 write.
  {
    const float* wrow = W_out + (size_t)((l < 20) ? l : 0) * 128;
    float acc = (l < 20) ? b_out[l] : 0.f;
    for (int j = 0; j < 64; ++j) acc += __shfl(gsa, j) * wrow[j];
    for (int j = 0; j < 64; ++j) acc += __shfl(gsb, j) * wrow[64 + j];
    if (l < 20) out0[n_glob * 20 + l] = acc;
  }
}

// ---------------------------------------------------------------------------
extern "C" void kernel_launch(void* const* d_in, const int* in_sizes, int n_in,
                              void* d_out, int out_size, void* d_ws, size_t ws_size,
                              hipStream_t stream) {
  const float* x     = (const float*)d_in[0];
  const float* W_in  = (const float*)d_in[1];
  const float* b_in  = (const float*)d_in[2];
  const float* W_rec = (const float*)d_in[3];
  const float* b_rec = (const float*)d_in[4];
  const float* W2    = (const float*)d_in[5];
  const float* b2    = (const float*)d_in[6];
  const float* k_t   = (const float*)d_in[7];
  const float* k_c   = (const float*)d_in[8];
  const float* W_p   = (const float*)d_in[9];
  const float* b_p   = (const float*)d_in[10];
  const float* W_out = (const float*)d_in[11];
  const float* b_out = (const float*)d_in[12];

  float* out      = (float*)d_out;
  float* out0     = out;                        // [4096,20]
  float* features = out + 81920;                // [16,4096,128]
  float* attended = out + 81920 + 8388608;      // [16,4096,128]

  float* ws  = (float*)d_ws;
  float* WrT = ws;                  // 16384 f32
  float* W2T = ws + 16384;          // 16384 f32
  float* WpT = ws + 32768;          // 16384 f32
  ushort* F2 = (ushort*)(ws + 49152);  // 2 x 128 x 704 f16 = 360 KB

  hipLaunchKernelGGL(k_prep, dim3(544), dim3(256), 0, stream,
                     W_rec, W2, W_p, W_in, WrT, W2T, WpT, F2);
  hipLaunchKernelGGL(k_gemm_scan, dim3(1024), dim3(256), 0, stream,
                     x, F2, b_in, b_rec, WrT, W2T, b2, WpT, b_p, W_out, b_out,
                     k_t, k_c, features, attended, out0);
}

// Round 15
// 73.520 us; speedup vs baseline: 1.7059x; 1.7059x over previous
//
#include <hip/hip_runtime.h>
#include <hip/hip_bf16.h>
#include <stdint.h>

// Problem constants: N=4096, T=16, D=700 (pad 704), C=128, NC=20
// Output layout (f32): out0 [4096,20] | features [16,4096,128] | attended [16,4096,128]

typedef __attribute__((ext_vector_type(8))) _Float16 half8;  // f16x8 MFMA frag
typedef __attribute__((ext_vector_type(4))) float f32x4;
typedef unsigned long long u64;

#define MFMA16F(a, b, c) __builtin_amdgcn_mfma_f32_16x16x32_f16(a, b, c, 0, 0, 0)

__device__ inline void gload16(const void* g, void* l) {
  __builtin_amdgcn_global_load_lds(
      (const __attribute__((address_space(1))) uint32_t*)g,
      (__attribute__((address_space(3))) uint32_t*)l, 16, 0, 0);
}

// ---------------------------------------------------------------------------
// f16 2-plane split with subnormal-avoiding scales:
//   a = h*2^-4 + l*2^-15 + ra,  |ra| <= 2^-24|a|   (RNE both planes)
// ---------------------------------------------------------------------------
__device__ inline void splitf16(float4 q0, float4 q1, half8& hh, half8& ll) {
  float f[8] = {q0.x, q0.y, q0.z, q0.w, q1.x, q1.y, q1.z, q1.w};
  _Float16 H[8], L[8];
#pragma unroll
  for (int j = 0; j < 8; ++j) {
    _Float16 h1 = (_Float16)(f[j] * 16.0f);          // RNE
    float r = fmaf((float)h1, -0.0625f, f[j]);       // exact residual
    L[j] = (_Float16)(r * 32768.0f);                 // 2^15, RNE
    H[j] = h1;
  }
  __builtin_memcpy(&hh, H, 16);
  __builtin_memcpy(&ll, L, 16);
}

// ---------------------------------------------------------------------------
// Prep: transpose WrT/W2T/WpT + split W_in into 2 f16 planes (k-pad 704)
//   b = p1*2^-8 + p2*2^-19 + rb, |rb| <= 2^-24|b|
// ---------------------------------------------------------------------------
__global__ void k_prep(const float* __restrict__ Wr, const float* __restrict__ W2,
                       const float* __restrict__ Wp, const float* __restrict__ Win,
                       float* __restrict__ WrT, float* __restrict__ W2T,
                       float* __restrict__ WpT, ushort* __restrict__ F2) {
  int idx = blockIdx.x * blockDim.x + threadIdx.x;
  if (idx < 3 * 16384) {
    int sel = idx >> 14;
    int r = idx & 16383;
    int j = r >> 7, c = r & 127;
    const float* src = (sel == 0) ? Wr : (sel == 1) ? W2 : Wp;
    float* dst = (sel == 0) ? WrT : (sel == 1) ? W2T : WpT;
    dst[r] = src[c * 128 + j];
  } else {
    int i2 = idx - 49152;
    if (i2 >= 128 * 704) return;
    int c = i2 / 704, d = i2 - c * 704;
    float w = (d < 700) ? Win[c * 700 + d] : 0.f;
    _Float16 b1 = (_Float16)(w * 256.0f);            // RNE, scale 2^8
    float r = fmaf((float)b1, -0.00390625f, w);      // exact residual
    _Float16 b2 = (_Float16)(r * 524288.0f);         // scale 2^19, RNE
    ushort u1, u2;
    __builtin_memcpy(&u1, &b1, 2);
    __builtin_memcpy(&u2, &b2, 2);
    F2[i2] = u1;
    F2[90112 + i2] = u2;
  }
}

// ---------------------------------------------------------------------------
// Fused GEMM + scan, 5 desynced blocks/CU. R10 K-loop EXACTLY (best known):
// tile 64x128, 256 threads, 4 waves, wave = 16 rows x 128 cols = ONE sample;
// A direct global->VGPR prefetched 1 kt ahead; B LDS dbuf 32KB via gload16;
// one __syncthreads per kt. LDS = 32768 EXACTLY: XWs[64][128] (XOR-swizzled)
// overlays the dbuf; scan scratch lives in the wave's own DEAD XWs rows
// (dumped after phase 1, wave-ordered). No launch-bounds register cap change
// (R13's spill lesson): VGPR stays ~R10 level, occupancy limited by LDS -> 5.
// ---------------------------------------------------------------------------
__global__ __launch_bounds__(256, 4) void k_gemm_scan(
    const float* __restrict__ x, const ushort* __restrict__ F2,
    const float* __restrict__ b_in, const float* __restrict__ b_rec,
    const float* __restrict__ WrT, const float* __restrict__ W2T,
    const float* __restrict__ b2, const float* __restrict__ WpT,
    const float* __restrict__ b_p, const float* __restrict__ W_out,
    const float* __restrict__ b_out, const float* __restrict__ k_t,
    const float* __restrict__ k_c, float* __restrict__ features,
    float* __restrict__ attended, float* __restrict__ out0) {
  __shared__ __align__(16) char lds[32768];  // B dbuf 2x16KB; then XWs[64][128]

  const int tid = threadIdx.x;
  const int w = tid >> 6;      // wave 0..3 = 16-row group = sample
  const int l = tid & 63;
  const int blk = blockIdx.x;
  const int lm = l & 15, kh = l >> 4;

  // --- A: direct per-lane loads; rows m = blk*64 + w*16 + lm contiguous in x.
  const float* xr = x + (size_t)(blk * 64 + w * 16 + lm) * 700;

  // --- B staging: 16 gload16/block-kt (2 planes x 8 col-groups), wave does 4.
  const ushort* bsrc[4];
  int bdst[4];
#pragma unroll
  for (int i = 0; i < 4; ++i) {
    int idx = w * 4 + i;
    int plane = idx >> 3, cg = idx & 7;
    int col = cg * 16 + (l >> 2);
    bsrc[i] = F2 + plane * 90112 + col * 704 + (((l & 3) ^ ((l >> 3) & 3)) * 8);
    bdst[i] = plane * 8192 + cg * 1024;
  }
  const int bkey = (lm >> 1) & 3;
  const int brd = lm * 64 + ((kh ^ bkey) * 16);

  f32x4 acc_h[8], acc_m[8];
#pragma unroll
  for (int j = 0; j < 8; ++j) {
    acc_h[j] = (f32x4){0.f, 0.f, 0.f, 0.f};
    acc_m[j] = (f32x4){0.f, 0.f, 0.f, 0.f};
  }

  auto STAGE = [&](int buf, int kt) {  // 4 gload_lds per wave
    const int k0 = kt * 32;
#pragma unroll
    for (int i = 0; i < 4; ++i)
      gload16(bsrc[i] + k0, lds + buf * 16384 + bdst[i]);
  };
  auto LOADA = [&](int kt, float4& q0, float4& q1) {
    const int k0 = kt * 32 + kh * 8;
    q0 = *(const float4*)(xr + k0);
    if (kt == 21 && kh == 3)
      q1 = make_float4(0.f, 0.f, 0.f, 0.f);  // k 700..703: B-pad is zero
    else
      q1 = *(const float4*)(xr + k0 + 4);
  };

  STAGE(0, 0);
  float4 qa, qb;
  LOADA(0, qa, qb);
  __syncthreads();
  int buf = 0;
  for (int kt = 0; kt < 22; ++kt) {
    float4 na = {}, nb = {};
    if (kt < 21) {
      STAGE(buf ^ 1, kt + 1);
      LOADA(kt + 1, na, nb);
    }
    half8 a1, a2;
    splitf16(qa, qb, a1, a2);
    const char* bb0 = lds + buf * 16384 + brd;
#pragma unroll
    for (int nf = 0; nf < 8; ++nf) {
      const char* bb = bb0 + nf * 1024;
      half8 b1 = *(const half8*)(bb);
      half8 b2f = *(const half8*)(bb + 8192);
      acc_h[nf] = MFMA16F(a1, b1, acc_h[nf]);
      acc_m[nf] = MFMA16F(a1, b2f, acc_m[nf]);
      acc_m[nf] = MFMA16F(a2, b1, acc_m[nf]);
    }
    __syncthreads();   // buf consumed by all waves; next-kt loads drained
    qa = na; qb = nb;
    buf ^= 1;
  }

  // --- Epilogue (wave-local): acc -> XWs[64][128] with XOR swizzle
  // colx = col ^ (((row>>2)&3)<<3); for rows kh*4+r the key is kh<<3.
  float* XWs = (float*)lds;
#pragma unroll
  for (int nf = 0; nf < 8; ++nf) {
    const int col = nf * 16 + lm;
    const float bias = b_in[col] + b_rec[col];
    const int colx = col ^ (kh << 3);
    const int rowb = w * 16 + kh * 4;
#pragma unroll
    for (int r = 0; r < 4; ++r)
      XWs[(rowb + r) * 128 + colx] =
          acc_h[nf][r] * 0.000244140625f +
          acc_m[nf][r] * 1.1920928955078125e-7f + bias;
  }
  // No barrier: wave w reads only its own rows w*16.. (wave-ordered LDS).

  // ================= wave-per-sample scan (no barriers at all) =============
  const int n_glob = blk * 4 + w;
  // Scratch lives in wave w's XWs region (bytes w*8192..), which is fully
  // dead after phase 1. fmask carried in regs (lane t) during phase 1.
  char* base = lds + w * 8192;
  u64* fmaskp = (u64*)base;              // [16][2] @ 0..255   (post-phase-1)
  float* gp  = (float*)(base + 512);     // [128]  @ 512..1023 (mean0, then g)
  float* tap = (float*)(base + 1024);    // [16]   @ 1024..1087
  float* cap = (float*)(base + 1088);    // [128]  @ 1088..1599

  const float b2a = b2[l], b2b = b2[l + 64];
  float v1a = 0.f, v1b = 0.f, v2a = 0.f, v2b = 0.f, fsa = 0.f, fsb = 0.f;
  u64 pm0 = 0ull, pm1 = 0ull;            // layer-1 spike masks (regs)
  u64 fm0 = 0ull, fm1 = 0ull;            // feature masks: lane t holds step t

  for (int t = 0; t < 16; ++t) {
    const float* xrow = XWs + (w * 16 + t) * 128;
    const int key = ((t >> 2) & 3) << 3;
    float ia = xrow[l ^ key];
    float ib = xrow[(l + 64) ^ key];
    u64 q0 = pm0, q1 = pm1;
    while (q0) { int j = __builtin_ctzll(q0); q0 &= q0 - 1;
      ia += WrT[j * 128 + l]; ib += WrT[j * 128 + l + 64]; }
    while (q1) { int j = __builtin_ctzll(q1); q1 &= q1 - 1;
      ia += WrT[(64 + j) * 128 + l]; ib += WrT[(64 + j) * 128 + l + 64]; }
    v1a = v1a + (ia - v1a) * 0.5f;       // decay_input=True, TAU=2
    bool sa = (v1a - 1.0f) >= 0.f; v1a = sa ? 0.f : v1a;
    v1b = v1b + (ib - v1b) * 0.5f;
    bool sb = (v1b - 1.0f) >= 0.f; v1b = sb ? 0.f : v1b;
    pm0 = __ballot((int)sa);
    pm1 = __ballot((int)sb);
    float xa = b2a, xb = b2b;
    u64 r0 = pm0, r1 = pm1;
    while (r0) { int j = __builtin_ctzll(r0); r0 &= r0 - 1;
      xa += W2T[j * 128 + l]; xb += W2T[j * 128 + l + 64]; }
    while (r1) { int j = __builtin_ctzll(r1); r1 &= r1 - 1;
      xa += W2T[(64 + j) * 128 + l]; xb += W2T[(64 + j) * 128 + l + 64]; }
    v2a = v2a + (xa - v2a) * 0.5f;
    bool fa = (v2a - 1.0f) >= 0.f; v2a = fa ? 0.f : v2a;
    v2b = v2b + (xb - v2b) * 0.5f;
    bool fb = (v2b - 1.0f) >= 0.f; v2b = fb ? 0.f : v2b;
    float ffa = fa ? 1.f : 0.f, ffb = fb ? 1.f : 0.f;
    features[(size_t)((t << 12) | n_glob) * 128 + l] = ffa;
    features[(size_t)((t << 12) | n_glob) * 128 + l + 64] = ffb;
    fsa += ffa; fsb += ffb;
    u64 f0 = __ballot((int)fa), f1 = __ballot((int)fb);
    if (l == t) { fm0 = f0; fm1 = f1; }  // lane t keeps step t's masks
  }

  // Dump scratch into the now-dead XWs rows (wave-ordered LDS; no barrier).
  if (l < 16) { fmaskp[l * 2 + 0] = fm0; fmaskp[l * 2 + 1] = fm1; }
  gp[l] = fsa * (1.f / 16.f);
  gp[l + 64] = fsb * (1.f / 16.f);

  // t_att: conv over T (SAME, width 3) of channel-mean popcounts + sigmoid
  if (l < 16) {
    float acc = 0.f;
#pragma unroll
    for (int j = 0; j < 3; ++j) {
      int tt = l - 1 + j;
      if (tt >= 0 && tt < 16) {
        float m = (float)(__popcll(fmaskp[tt * 2 + 0]) +
                          __popcll(fmaskp[tt * 2 + 1])) * (1.f / 128.f);
        acc += k_t[j] * m;
      }
    }
    tap[l] = 1.f / (1.f + expf(-acc));
  }
  // c_att: conv over C (SAME, width 3) of mean0 + sigmoid (both channels)
  {
    float mm1 = (l == 0) ? 0.f : gp[l - 1];
    float acc = k_c[0] * mm1 + k_c[1] * gp[l] + k_c[2] * gp[l + 1];
    cap[l] = 1.f / (1.f + expf(-acc));
    float np1 = (l == 63) ? 0.f : gp[l + 65];
    float acc2 = k_c[0] * gp[l + 63] + k_c[1] * gp[l + 64] + k_c[2] * np1;
    cap[l + 64] = 1.f / (1.f + expf(-acc2));
  }

  // ---- phase 2: attended + LIF layer3 + spike-count (wave-local) ----
  const float bpa = b_p[l], bpb = b_p[l + 64];
  const float caa = cap[l], cab = cap[l + 64];
  float v3a = 0.f, v3b = 0.f, ssa = 0.f, ssb = 0.f;
  for (int t = 0; t < 16; ++t) {
    u64 m0 = fmaskp[t * 2 + 0], m1 = fmaskp[t * 2 + 1];
    float tat = tap[t];
    bool ba = (m0 >> l) & 1, bb = (m1 >> l) & 1;
    attended[(size_t)((t << 12) | n_glob) * 128 + l] = ba ? tat * caa : 0.f;
    attended[(size_t)((t << 12) | n_glob) * 128 + l + 64] = bb ? tat * cab : 0.f;
    float ha = bpa, hb = bpb;
    u64 q0 = m0, q1 = m1;
    while (q0) { int j = __builtin_ctzll(q0); q0 &= q0 - 1;
      float w_ = tat * cap[j];
      ha += w_ * WpT[j * 128 + l]; hb += w_ * WpT[j * 128 + l + 64]; }
    while (q1) { int j = __builtin_ctzll(q1); q1 &= q1 - 1;
      float w_ = tat * cap[64 + j];
      ha += w_ * WpT[(64 + j) * 128 + l]; hb += w_ * WpT[(64 + j) * 128 + l + 64]; }
    v3a = v3a + (ha - v3a) * 0.5f;
    bool sa = (v3a - 1.0f) >= 0.f; v3a = sa ? 0.f : v3a;
    ssa += sa ? 1.f : 0.f;
    v3b = v3b + (hb - v3b) * 0.5f;
    bool sb = (v3b - 1.0f) >= 0.f; v3b = sb ? 0.f : v3b;
    ssb += sb ? 1.f : 0.f;
  }
  gp[l] = ssa * (1.f / 16.f);      // overwrite mean0 temp (dead)
  gp[l + 64] = ssb * (1.f / 16.f);
  if (l < 20) {
    float acc = b_out[l];
    for (int j = 0; j < 128; ++j) acc += gp[j] * W_out[l * 128 + j];
    out0[n_glob * 20 + l] = acc;
  }
}

// ---------------------------------------------------------------------------
extern "C" void kernel_launch(void* const* d_in, const int* in_sizes, int n_in,
                              void* d_out, int out_size, void* d_ws, size_t ws_size,
                              hipStream_t stream) {
  const float* x     = (const float*)d_in[0];
  const float* W_in  = (const float*)d_in[1];
  const float* b_in  = (const float*)d_in[2];
  const float* W_rec = (const float*)d_in[3];
  const float* b_rec = (const float*)d_in[4];
  const float* W2    = (const float*)d_in[5];
  const float* b2    = (const float*)d_in[6];
  const float* k_t   = (const float*)d_in[7];
  const float* k_c   = (const float*)d_in[8];
  const float* W_p   = (const float*)d_in[9];
  const float* b_p   = (const float*)d_in[10];
  const float* W_out = (const float*)d_in[11];
  const float* b_out = (const float*)d_in[12];

  float* out      = (float*)d_out;
  float* out0     = out;                        // [4096,20]
  float* features = out + 81920;                // [16,4096,128]
  float* attended = out + 81920 + 8388608;      // [16,4096,128]

  float* ws  = (float*)d_ws;
  float* WrT = ws;                  // 16384 f32
  float* W2T = ws + 16384;          // 16384 f32
  float* WpT = ws + 32768;          // 16384 f32
  ushort* F2 = (ushort*)(ws + 49152);  // 2 x 128 x 704 f16 = 360 KB

  hipLaunchKernelGGL(k_prep, dim3(544), dim3(256), 0, stream,
                     W_rec, W2, W_p, W_in, WrT, W2T, WpT, F2);
  hipLaunchKernelGGL(k_gemm_scan, dim3(1024), dim3(256), 0, stream,
                     x, F2, b_in, b_rec, WrT, W2T, b2, WpT, b_p, W_out, b_out,
                     k_t, k_c, features, attended, out0);
}